// Round 2
// baseline (1000.491 us; speedup 1.0000x reference)
//
#include <hip/hip_runtime.h>
#include <hip/hip_bf16.h>
#include <math.h>

#define L_SEQ  2048
#define NBATCH 2
#define DMODEL 1024
#define DINNER 2048
#define DSTATE 16
#define DTRANK 64
#define MTOK   (NBATCH * L_SEQ)   // 4096

typedef __hip_bfloat16 bf16_t;
typedef __attribute__((ext_vector_type(8))) short bf16x8;   // 8 bf16 = 4 VGPRs
typedef __attribute__((ext_vector_type(4))) float f32x4;

__device__ __forceinline__ float  bf2f(bf16_t v) { return __bfloat162float(v); }
__device__ __forceinline__ bf16_t f2bf(float v)  { return __float2bfloat16(v); }

// fp32 -> bf16 cast (inputs arrive fp32; MFMA wants bf16)
__global__ __launch_bounds__(256)
void castf2b_kernel(const float* __restrict__ in, bf16_t* __restrict__ out, int n)
{
    int i = blockIdx.x * 256 + threadIdx.x;
    if (i < n) out[i] = f2bf(in[i]);
}

// NT GEMM: C[m,n] = sum_k A[m,k] * Bw[n,k], both K-contiguous (row-major), bf16 in.
// Tile: BM=32*TM x BN=32*TN, 4 waves (2x2), wave does TM x TN mfma_16x16x32 tiles.
// EPI: 1 = bf16 store; 2 = fp32 atomicAdd (split-K); 3 = softplus(acc+bias) fp32; 4 = fp32 store
template<int TM, int TN, int EPI, int KSPLIT>
__global__ __launch_bounds__(256)
void gemm_nt(const bf16_t* __restrict__ A, const bf16_t* __restrict__ Bw,
             int K, int lda, int ldb, int ldo,
             float* __restrict__ outF, bf16_t* __restrict__ outB,
             const float* __restrict__ bias)
{
    constexpr int BM = 32 * TM, BN = 32 * TN;
    constexpr int NA   = BM / 16;          // A staging issues (64 x 16B chunks each)
    constexpr int NISS = NA + BN / 16;     // total issues per K-iter
    __shared__ bf16_t As[BM * 32];
    __shared__ bf16_t Bs[BN * 32];

    const int tid  = threadIdx.x;
    const int w    = tid >> 6;
    const int lane = tid & 63;
    const int wm   = w >> 1, wn = w & 1;
    const int bm   = blockIdx.x * BM;
    const int bn   = blockIdx.y * BN;
    const int Kc   = K / KSPLIT;
    const int kbeg = blockIdx.z * Kc;

    f32x4 acc[TM][TN];
#pragma unroll
    for (int i = 0; i < TM; ++i)
#pragma unroll
        for (int j = 0; j < TN; ++j)
            acc[i][j] = (f32x4){0.f, 0.f, 0.f, 0.f};

    const int mr = lane & 15;   // m (or n) within 16-tile
    const int kq = lane >> 4;   // k-quarter 0..3

    for (int kt = kbeg; kt < kbeg + Kc; kt += 32) {
        // ---- stage A,B tiles via async global->LDS (16B/lane, wave-uniform LDS base)
        for (int it = w; it < NISS; it += 4) {
            const bf16_t* gp;
            char* lp;
            if (it < NA) {
                int chunk = it * 64 + lane;
                int row = chunk >> 2, q = chunk & 3;
                gp = A + (size_t)(bm + row) * lda + kt + q * 8;
                lp = (char*)As + it * 1024;
            } else {
                int chunk = (it - NA) * 64 + lane;
                int row = chunk >> 2, q = chunk & 3;
                gp = Bw + (size_t)(bn + row) * ldb + kt + q * 8;
                lp = (char*)Bs + (it - NA) * 1024;
            }
            __builtin_amdgcn_global_load_lds(
                (const __attribute__((address_space(1))) void*)gp,
                (__attribute__((address_space(3))) void*)lp, 16, 0, 0);
        }
        __syncthreads();

        // ---- fragments + MFMA (A[m=lane&15][k=(lane>>4)*8+j], B mirrors)
        bf16x8 af[TM], bfv[TN];
#pragma unroll
        for (int mi = 0; mi < TM; ++mi)
            af[mi] = *(const bf16x8*)&As[(wm * 16 * TM + mi * 16 + mr) * 32 + kq * 8];
#pragma unroll
        for (int ni = 0; ni < TN; ++ni)
            bfv[ni] = *(const bf16x8*)&Bs[(wn * 16 * TN + ni * 16 + mr) * 32 + kq * 8];
#pragma unroll
        for (int mi = 0; mi < TM; ++mi)
#pragma unroll
            for (int ni = 0; ni < TN; ++ni)
                acc[mi][ni] = __builtin_amdgcn_mfma_f32_16x16x32_bf16(
                    af[mi], bfv[ni], acc[mi][ni], 0, 0, 0);
        __syncthreads();
    }

    // ---- epilogue: C/D layout col=lane&15, row=(lane>>4)*4+reg  [m89/m91 verified]
#pragma unroll
    for (int mi = 0; mi < TM; ++mi) {
#pragma unroll
        for (int ni = 0; ni < TN; ++ni) {
#pragma unroll
            for (int r = 0; r < 4; ++r) {
                int row = bm + wm * 16 * TM + mi * 16 + kq * 4 + r;
                int col = bn + wn * 16 * TN + ni * 16 + mr;
                float v = acc[mi][ni][r];
                if (EPI == 1) {
                    outB[(size_t)row * ldo + col] = f2bf(v);
                } else if (EPI == 2) {
                    atomicAdd(&outF[(size_t)row * ldo + col], v);
                } else if (EPI == 3) { // softplus(v + bias[col])
                    v += bias[col];
                    v = (v > 20.f) ? v : log1pf(__expf(v));
                    outF[(size_t)row * ldo + col] = v;
                } else { // EPI == 4: plain fp32 store
                    outF[(size_t)row * ldo + col] = v;
                }
            }
        }
    }
}

// depthwise causal conv (width 4) + bias + SiLU. x = first half of xz [M, 4096] bf16.
__global__ __launch_bounds__(256)
void conv_silu_kernel(const bf16_t* __restrict__ xz, const float* __restrict__ cw,
                      const float* __restrict__ cb, bf16_t* __restrict__ xcb)
{
    int idx = blockIdx.x * 256 + threadIdx.x;      // < MTOK*DINNER
    int d = idx & (DINNER - 1);
    int m = idx >> 11;
    int t = m & (L_SEQ - 1);
    float acc = cb[d];
#pragma unroll
    for (int k = 0; k < 4; ++k) {
        int tt = t - 3 + k;
        if (tt >= 0)
            acc += bf2f(xz[(size_t)(m - 3 + k) * (2 * DINNER) + d]) * cw[d * 4 + k];
    }
    float s = acc / (1.f + __expf(-acc));
    xcb[idx] = f2bf(s);
}

// cast dt columns (0..63) of xdbl [M,96] fp32 -> dtb [M,64] bf16 (A input of dt GEMM)
__global__ __launch_bounds__(256)
void dtcast_kernel(const float* __restrict__ xdbl, bf16_t* __restrict__ dtb)
{
    int i = blockIdx.x * 256 + threadIdx.x;        // < MTOK*64
    int m = i >> 6, r = i & 63;
    dtb[i] = f2bf(xdbl[(size_t)m * 96 + r]);
}

// selective scan: thread = (b, d, n). 16 lanes (n) share channel d; shfl-reduce for y.
__global__ __launch_bounds__(256)
void scan_kernel(const float* __restrict__ dlt, const bf16_t* __restrict__ u,
                 const float* __restrict__ xdbl, const float* __restrict__ A_log,
                 float* __restrict__ ys)
{
    int b  = blockIdx.x >> 7;                // 128 blocks per batch
    int d0 = (blockIdx.x & 127) * 16;
    int n  = threadIdx.x & 15;
    int dl = threadIdx.x >> 4;
    int d  = d0 + dl;

    float Av = -expf(A_log[d * DSTATE + n]);
    const float*  dp = dlt + (size_t)b * L_SEQ * DINNER + d;
    const bf16_t* up = u   + (size_t)b * L_SEQ * DINNER + d;
    const float*  bp = xdbl + (size_t)b * L_SEQ * 96 + DTRANK + n;      // B_t[n]
    const float*  cp = bp + DSTATE;                                      // C_t[n]
    float* yo = ys + (size_t)b * L_SEQ * DINNER + d;

    float h = 0.f;
    float cd = dp[0], cu = bf2f(up[0]), cB = bp[0], cC = cp[0];
    for (int t = 0; t < L_SEQ; ++t) {
        int tn = (t + 1 < L_SEQ) ? t + 1 : t;
        // prefetch next step (independent of h-chain)
        float nd = dp[(size_t)tn * DINNER];
        float nu = bf2f(up[(size_t)tn * DINNER]);
        float nB = bp[(size_t)tn * 96];
        float nC = cp[(size_t)tn * 96];

        float dA = __expf(cd * Av);
        h = fmaf(dA, h, cd * cu * cB);
        float p = h * cC;
        p += __shfl_xor(p, 8, 16);
        p += __shfl_xor(p, 4, 16);
        p += __shfl_xor(p, 2, 16);
        p += __shfl_xor(p, 1, 16);
        if (n == 0) yo[(size_t)t * DINNER] = p;

        cd = nd; cu = nu; cB = nB; cC = nC;
    }
}

// y = (y_scan + x_conv * D_skip) * silu(z)  -> bf16 (A input of out_proj)
__global__ __launch_bounds__(256)
void gate_kernel(const bf16_t* __restrict__ xz, const bf16_t* __restrict__ xcb,
                 const float* __restrict__ ys, const float* __restrict__ Dskip,
                 bf16_t* __restrict__ yg)
{
    int idx = blockIdx.x * 256 + threadIdx.x;
    int d = idx & (DINNER - 1);
    int m = idx >> 11;
    float z  = bf2f(xz[(size_t)m * (2 * DINNER) + DINNER + d]);
    float yv = (ys[idx] + bf2f(xcb[idx]) * Dskip[d]) * (z / (1.f + __expf(-z)));
    yg[idx] = f2bf(yv);
}

extern "C" void kernel_launch(void* const* d_in, const int* in_sizes, int n_in,
                              void* d_out, int out_size, void* d_ws, size_t ws_size,
                              hipStream_t stream)
{
    (void)in_sizes; (void)n_in; (void)out_size; (void)ws_size;
    // Inputs are fp32 per the reference dtypes.
    const float* hs     = (const float*)d_in[0];   // [2,2048,1024]
    const float* W_in   = (const float*)d_in[1];   // [4096,1024]
    const float* conv_w = (const float*)d_in[2];   // [2048,4]
    const float* conv_b = (const float*)d_in[3];   // [2048]
    const float* W_xp   = (const float*)d_in[4];   // [96,2048]
    const float* W_dt   = (const float*)d_in[5];   // [2048,64]
    const float* b_dt   = (const float*)d_in[6];   // [2048]
    const float* A_log  = (const float*)d_in[7];   // [2048,16]
    const float* D_skip = (const float*)d_in[8];   // [2048]
    const float* W_out  = (const float*)d_in[9];   // [1024,2048]

    char* ws = (char*)d_ws;
    bf16_t* xz   = (bf16_t*)(ws + 0);            // [M,4096] bf16   33,554,432 B
    bf16_t* xcb  = (bf16_t*)(ws + 33554432);     // [M,2048] bf16   16,777,216 B
    float*  dlt  = (float*) (ws + 50331648);     // [M,2048] f32    33,554,432 B
    float*  ysv  = (float*) (ws + 83886080);     // [M,2048] f32    33,554,432 B
    float*  xdbl = (float*) (ws + 117440512);    // [M,96]  f32      1,572,864 B
    bf16_t* dtb  = (bf16_t*)(ws + 119013376);    // [M,64]  bf16       524,288 B
    bf16_t* Wxb  = (bf16_t*)(ws + 119537664);    // [96,2048]          393,216 B
    bf16_t* Wdb  = (bf16_t*)(ws + 119930880);    // [2048,64]          262,144 B
    bf16_t* Wob  = (bf16_t*)(ws + 120193024);    // [1024,2048]      4,194,304 B
    bf16_t* hsb  = (bf16_t*)(ws + 124387328);    // [M,1024]         8,388,608 B
    bf16_t* Wib  = (bf16_t*)(ws + 132775936);    // [4096,1024]      8,388,608 B
    bf16_t* yg   = (bf16_t*)(ws + 50331648);     // [M,2048] bf16 (aliases dlt; dead after scan)
    // total ws used: 141,164,544 B

    // 0. cast fp32 inputs to bf16 for MFMA
    castf2b_kernel<<<(MTOK*DMODEL)/256, 256, 0, stream>>>(hs,    hsb, MTOK*DMODEL);
    castf2b_kernel<<<(4096*1024)/256,  256, 0, stream>>>(W_in,  Wib, 4096*1024);
    castf2b_kernel<<<(96*2048)/256,    256, 0, stream>>>(W_xp,  Wxb, 96*2048);
    castf2b_kernel<<<(2048*64)/256,    256, 0, stream>>>(W_dt,  Wdb, 2048*64);
    castf2b_kernel<<<(1024*2048)/256,  256, 0, stream>>>(W_out, Wob, 1024*2048);

    // 1. in_proj: xz = hs @ W_in^T   (M=4096, N=4096, K=1024)
    gemm_nt<4,4,1,1><<<dim3(MTOK/128, 4096/128, 1), 256, 0, stream>>>(
        hsb, Wib, DMODEL, DMODEL, DMODEL, 2*DINNER, nullptr, xz, nullptr);

    // 2. depthwise conv + SiLU
    conv_silu_kernel<<<MTOK*DINNER/256, 256, 0, stream>>>(xz, conv_w, conv_b, xcb);

    // 3. x_proj: xdbl = x_conv @ W_xproj^T  (N=96, K=2048) split-K=8 with atomic epilogue
    hipMemsetAsync(xdbl, 0, (size_t)MTOK*96*4, stream);
    gemm_nt<4,3,2,8><<<dim3(MTOK/128, 1, 8), 256, 0, stream>>>(
        xcb, Wxb, DINNER, DINNER, DINNER, 96, xdbl, nullptr, nullptr);

    // 4. cast dt block to bf16
    dtcast_kernel<<<MTOK*64/256, 256, 0, stream>>>(xdbl, dtb);

    // 5. delta = softplus(dt @ W_dt^T + b_dt)  (N=2048, K=64)
    gemm_nt<4,4,3,1><<<dim3(MTOK/128, DINNER/128, 1), 256, 0, stream>>>(
        dtb, Wdb, DTRANK, DTRANK, DTRANK, DINNER, dlt, nullptr, b_dt);

    // 6. selective scan
    scan_kernel<<<NBATCH*(DINNER/16), 256, 0, stream>>>(dlt, xcb, xdbl, A_log, ysv);

    // 7. skip + gate
    gate_kernel<<<MTOK*DINNER/256, 256, 0, stream>>>(xz, xcb, ysv, D_skip, yg);

    // 8. out_proj: out = y @ W_out^T  (N=1024, K=2048) -> fp32 d_out
    gemm_nt<4,4,4,1><<<dim3(MTOK/128, DMODEL/128, 1), 256, 0, stream>>>(
        yg, Wob, DINNER, DINNER, DINNER, DMODEL, (float*)d_out, nullptr, nullptr);
}

// Round 3
// 425.965 us; speedup vs baseline: 2.3488x; 2.3488x over previous
//
#include <hip/hip_runtime.h>
#include <hip/hip_bf16.h>
#include <math.h>

#define L_SEQ  2048
#define NBATCH 2
#define DMODEL 1024
#define DINNER 2048
#define DSTATE 16
#define DTRANK 64
#define MTOK   (NBATCH * L_SEQ)   // 4096
#define NC     32                 // scan chunks per sequence
#define TCH    (L_SEQ / NC)       // 64 steps per chunk

typedef __hip_bfloat16 bf16_t;
typedef __attribute__((ext_vector_type(8))) short bf16x8;   // 8 bf16 = 4 VGPRs
typedef __attribute__((ext_vector_type(4))) float f32x4;

__device__ __forceinline__ float  bf2f(bf16_t v) { return __bfloat162float(v); }
__device__ __forceinline__ bf16_t f2bf(float v)  { return __float2bfloat16(v); }

// fp32 -> bf16 cast (inputs arrive fp32; MFMA wants bf16)
__global__ __launch_bounds__(256)
void castf2b_kernel(const float* __restrict__ in, bf16_t* __restrict__ out, int n)
{
    int i = blockIdx.x * 256 + threadIdx.x;
    if (i < n) out[i] = f2bf(in[i]);
}

// NT GEMM: C[m,n] = sum_k A[m,k] * Bw[n,k], both K-contiguous (row-major), bf16 in.
// EPI: 1 = bf16 store; 2 = fp32 atomicAdd (split-K); 3 = softplus(acc+bias) fp32; 4 = fp32 store
template<int TM, int TN, int EPI, int KSPLIT>
__global__ __launch_bounds__(256)
void gemm_nt(const bf16_t* __restrict__ A, const bf16_t* __restrict__ Bw,
             int K, int lda, int ldb, int ldo,
             float* __restrict__ outF, bf16_t* __restrict__ outB,
             const float* __restrict__ bias)
{
    constexpr int BM = 32 * TM, BN = 32 * TN;
    constexpr int NA   = BM / 16;
    constexpr int NISS = NA + BN / 16;
    __shared__ bf16_t As[BM * 32];
    __shared__ bf16_t Bs[BN * 32];

    const int tid  = threadIdx.x;
    const int w    = tid >> 6;
    const int lane = tid & 63;
    const int wm   = w >> 1, wn = w & 1;
    const int bm   = blockIdx.x * BM;
    const int bn   = blockIdx.y * BN;
    const int Kc   = K / KSPLIT;
    const int kbeg = blockIdx.z * Kc;

    f32x4 acc[TM][TN];
#pragma unroll
    for (int i = 0; i < TM; ++i)
#pragma unroll
        for (int j = 0; j < TN; ++j)
            acc[i][j] = (f32x4){0.f, 0.f, 0.f, 0.f};

    const int mr = lane & 15;
    const int kq = lane >> 4;

    for (int kt = kbeg; kt < kbeg + Kc; kt += 32) {
        for (int it = w; it < NISS; it += 4) {
            const bf16_t* gp;
            char* lp;
            if (it < NA) {
                int chunk = it * 64 + lane;
                int row = chunk >> 2, q = chunk & 3;
                gp = A + (size_t)(bm + row) * lda + kt + q * 8;
                lp = (char*)As + it * 1024;
            } else {
                int chunk = (it - NA) * 64 + lane;
                int row = chunk >> 2, q = chunk & 3;
                gp = Bw + (size_t)(bn + row) * ldb + kt + q * 8;
                lp = (char*)Bs + (it - NA) * 1024;
            }
            __builtin_amdgcn_global_load_lds(
                (const __attribute__((address_space(1))) void*)gp,
                (__attribute__((address_space(3))) void*)lp, 16, 0, 0);
        }
        __syncthreads();

        bf16x8 af[TM], bfv[TN];
#pragma unroll
        for (int mi = 0; mi < TM; ++mi)
            af[mi] = *(const bf16x8*)&As[(wm * 16 * TM + mi * 16 + mr) * 32 + kq * 8];
#pragma unroll
        for (int ni = 0; ni < TN; ++ni)
            bfv[ni] = *(const bf16x8*)&Bs[(wn * 16 * TN + ni * 16 + mr) * 32 + kq * 8];
#pragma unroll
        for (int mi = 0; mi < TM; ++mi)
#pragma unroll
            for (int ni = 0; ni < TN; ++ni)
                acc[mi][ni] = __builtin_amdgcn_mfma_f32_16x16x32_bf16(
                    af[mi], bfv[ni], acc[mi][ni], 0, 0, 0);
        __syncthreads();
    }

#pragma unroll
    for (int mi = 0; mi < TM; ++mi) {
#pragma unroll
        for (int ni = 0; ni < TN; ++ni) {
#pragma unroll
            for (int r = 0; r < 4; ++r) {
                int row = bm + wm * 16 * TM + mi * 16 + kq * 4 + r;
                int col = bn + wn * 16 * TN + ni * 16 + mr;
                float v = acc[mi][ni][r];
                if (EPI == 1) {
                    outB[(size_t)row * ldo + col] = f2bf(v);
                } else if (EPI == 2) {
                    atomicAdd(&outF[(size_t)row * ldo + col], v);
                } else if (EPI == 3) {
                    v += bias[col];
                    v = (v > 20.f) ? v : log1pf(__expf(v));
                    outF[(size_t)row * ldo + col] = v;
                } else {
                    outF[(size_t)row * ldo + col] = v;
                }
            }
        }
    }
}

// depthwise causal conv (width 4) + bias + SiLU. x = first half of xz [M, 4096] bf16.
__global__ __launch_bounds__(256)
void conv_silu_kernel(const bf16_t* __restrict__ xz, const float* __restrict__ cw,
                      const float* __restrict__ cb, bf16_t* __restrict__ xcb)
{
    int idx = blockIdx.x * 256 + threadIdx.x;
    int d = idx & (DINNER - 1);
    int m = idx >> 11;
    int t = m & (L_SEQ - 1);
    float acc = cb[d];
#pragma unroll
    for (int k = 0; k < 4; ++k) {
        int tt = t - 3 + k;
        if (tt >= 0)
            acc += bf2f(xz[(size_t)(m - 3 + k) * (2 * DINNER) + d]) * cw[d * 4 + k];
    }
    float s = acc / (1.f + __expf(-acc));
    xcb[idx] = f2bf(s);
}

// cast dt columns (0..63) of xdbl [M,96] fp32 -> dtb [M,64] bf16
__global__ __launch_bounds__(256)
void dtcast_kernel(const float* __restrict__ xdbl, bf16_t* __restrict__ dtb)
{
    int i = blockIdx.x * 256 + threadIdx.x;
    int m = i >> 6, r = i & 63;
    dtb[i] = f2bf(xdbl[(size_t)m * 96 + r]);
}

// ---------- chunked selective scan ----------
// Pass 1: per (b, chunk, d) thread: chunk-local scan from h=0; emit final h and decay product.
__global__ __launch_bounds__(256)
void scan_part1(const float* __restrict__ dlt, const bf16_t* __restrict__ u,
                const float* __restrict__ xdbl, const float* __restrict__ A_log,
                float* __restrict__ hloc, float* __restrict__ aprod)
{
    int bx = blockIdx.x;
    int dblk = bx & 7;
    int c    = (bx >> 3) & (NC - 1);
    int b    = bx >> 8;
    int d    = dblk * 256 + threadIdx.x;
    int m0   = b * L_SEQ + c * TCH;

    __shared__ float BC[TCH][32];   // [:,0:16]=B, [:,16:32]=C
    for (int i = threadIdx.x; i < TCH * 32; i += 256) {
        int r = i >> 5, cc = i & 31;
        BC[r][cc] = xdbl[(size_t)(m0 + r) * 96 + 64 + cc];
    }
    __syncthreads();

    float Av[16];
#pragma unroll
    for (int n = 0; n < 16; ++n) Av[n] = -__expf(A_log[d * 16 + n]);

    const float*  dp = dlt + (size_t)m0 * DINNER + d;
    const bf16_t* up = u   + (size_t)m0 * DINNER + d;

    float h[16], ca[16];
#pragma unroll
    for (int n = 0; n < 16; ++n) { h[n] = 0.f; ca[n] = 1.f; }

    float dv[8], uv[8];
#pragma unroll
    for (int j = 0; j < 8; ++j) {
        dv[j] = dp[(size_t)j * DINNER];
        uv[j] = bf2f(up[(size_t)j * DINNER]);
    }
    for (int tb = 0; tb < TCH; tb += 8) {
        float dn[8] = {0}, un[8] = {0};
        if (tb + 8 < TCH) {
#pragma unroll
            for (int j = 0; j < 8; ++j) {
                dn[j] = dp[(size_t)(tb + 8 + j) * DINNER];
                un[j] = bf2f(up[(size_t)(tb + 8 + j) * DINNER]);
            }
        }
#pragma unroll
        for (int j = 0; j < 8; ++j) {
            int t = tb + j;
            float dt_t = dv[j];
            float dbu  = dt_t * uv[j];
#pragma unroll
            for (int n = 0; n < 16; ++n) {
                float dA = __expf(dt_t * Av[n]);
                h[n] = fmaf(dA, h[n], dbu * BC[t][n]);
                ca[n] *= dA;
            }
        }
#pragma unroll
        for (int j = 0; j < 8; ++j) { dv[j] = dn[j]; uv[j] = un[j]; }
    }

    size_t o = (((size_t)b * NC + c) * DINNER + d) * 16;
#pragma unroll
    for (int n = 0; n < 16; n += 4) {
        *(f32x4*)&hloc[o + n]  = (f32x4){h[n], h[n+1], h[n+2], h[n+3]};
        *(f32x4*)&aprod[o + n] = (f32x4){ca[n], ca[n+1], ca[n+2], ca[n+3]};
    }
}

// Pass 2: serial carry over chunks (tiny): Hin[c] = H before chunk c.
__global__ __launch_bounds__(256)
void scan_part2(const float* __restrict__ hloc, const float* __restrict__ aprod,
                float* __restrict__ Hin)
{
    int idx = blockIdx.x * 256 + threadIdx.x;   // < 2*DINNER*16
    int b  = idx >> 15;
    int dn = idx & 32767;
    float H = 0.f;
    size_t o = (size_t)b * NC * DINNER * 16 + dn;
    float a = aprod[o], hl = hloc[o];
    for (int c = 0; c < NC; ++c) {
        size_t on = o + (size_t)(c + 1) * DINNER * 16;
        float an = 0.f, hn = 0.f;
        if (c + 1 < NC) { an = aprod[on]; hn = hloc[on]; }
        Hin[o + (size_t)c * 0 + (size_t)c * DINNER * 16] = H;
        H = fmaf(a, H, hl);
        a = an; hl = hn;
    }
}

// Pass 3: chunk scan seeded with Hin, compute y.
__global__ __launch_bounds__(256)
void scan_part3(const float* __restrict__ dlt, const bf16_t* __restrict__ u,
                const float* __restrict__ xdbl, const float* __restrict__ A_log,
                const float* __restrict__ Hin, float* __restrict__ ys)
{
    int bx = blockIdx.x;
    int dblk = bx & 7;
    int c    = (bx >> 3) & (NC - 1);
    int b    = bx >> 8;
    int d    = dblk * 256 + threadIdx.x;
    int m0   = b * L_SEQ + c * TCH;

    __shared__ float BC[TCH][32];
    for (int i = threadIdx.x; i < TCH * 32; i += 256) {
        int r = i >> 5, cc = i & 31;
        BC[r][cc] = xdbl[(size_t)(m0 + r) * 96 + 64 + cc];
    }
    __syncthreads();

    float Av[16];
#pragma unroll
    for (int n = 0; n < 16; ++n) Av[n] = -__expf(A_log[d * 16 + n]);

    const float*  dp = dlt + (size_t)m0 * DINNER + d;
    const bf16_t* up = u   + (size_t)m0 * DINNER + d;
    float* yo = ys + (size_t)m0 * DINNER + d;

    size_t o = (((size_t)b * NC + c) * DINNER + d) * 16;
    float h[16];
#pragma unroll
    for (int n = 0; n < 16; n += 4) {
        f32x4 hv = *(const f32x4*)&Hin[o + n];
        h[n] = hv[0]; h[n+1] = hv[1]; h[n+2] = hv[2]; h[n+3] = hv[3];
    }

    float dv[8], uv[8];
#pragma unroll
    for (int j = 0; j < 8; ++j) {
        dv[j] = dp[(size_t)j * DINNER];
        uv[j] = bf2f(up[(size_t)j * DINNER]);
    }
    for (int tb = 0; tb < TCH; tb += 8) {
        float dn[8] = {0}, un[8] = {0};
        if (tb + 8 < TCH) {
#pragma unroll
            for (int j = 0; j < 8; ++j) {
                dn[j] = dp[(size_t)(tb + 8 + j) * DINNER];
                un[j] = bf2f(up[(size_t)(tb + 8 + j) * DINNER]);
            }
        }
#pragma unroll
        for (int j = 0; j < 8; ++j) {
            int t = tb + j;
            float dt_t = dv[j];
            float dbu  = dt_t * uv[j];
            float y0 = 0.f, y1 = 0.f, y2 = 0.f, y3 = 0.f;
#pragma unroll
            for (int n = 0; n < 16; n += 4) {
                float dA0 = __expf(dt_t * Av[n]);
                float dA1 = __expf(dt_t * Av[n+1]);
                float dA2 = __expf(dt_t * Av[n+2]);
                float dA3 = __expf(dt_t * Av[n+3]);
                h[n]   = fmaf(dA0, h[n],   dbu * BC[t][n]);
                h[n+1] = fmaf(dA1, h[n+1], dbu * BC[t][n+1]);
                h[n+2] = fmaf(dA2, h[n+2], dbu * BC[t][n+2]);
                h[n+3] = fmaf(dA3, h[n+3], dbu * BC[t][n+3]);
                y0 = fmaf(h[n],   BC[t][16+n],   y0);
                y1 = fmaf(h[n+1], BC[t][16+n+1], y1);
                y2 = fmaf(h[n+2], BC[t][16+n+2], y2);
                y3 = fmaf(h[n+3], BC[t][16+n+3], y3);
            }
            yo[(size_t)t * DINNER] = (y0 + y1) + (y2 + y3);
        }
#pragma unroll
        for (int j = 0; j < 8; ++j) { dv[j] = dn[j]; uv[j] = un[j]; }
    }
}

// y = (y_scan + x_conv * D_skip) * silu(z)  -> bf16
__global__ __launch_bounds__(256)
void gate_kernel(const bf16_t* __restrict__ xz, const bf16_t* __restrict__ xcb,
                 const float* __restrict__ ys, const float* __restrict__ Dskip,
                 bf16_t* __restrict__ yg)
{
    int idx = blockIdx.x * 256 + threadIdx.x;
    int d = idx & (DINNER - 1);
    int m = idx >> 11;
    float z  = bf2f(xz[(size_t)m * (2 * DINNER) + DINNER + d]);
    float yv = (ys[idx] + bf2f(xcb[idx]) * Dskip[d]) * (z / (1.f + __expf(-z)));
    yg[idx] = f2bf(yv);
}

extern "C" void kernel_launch(void* const* d_in, const int* in_sizes, int n_in,
                              void* d_out, int out_size, void* d_ws, size_t ws_size,
                              hipStream_t stream)
{
    (void)in_sizes; (void)n_in; (void)out_size; (void)ws_size;
    const float* hs     = (const float*)d_in[0];
    const float* W_in   = (const float*)d_in[1];
    const float* conv_w = (const float*)d_in[2];
    const float* conv_b = (const float*)d_in[3];
    const float* W_xp   = (const float*)d_in[4];
    const float* W_dt   = (const float*)d_in[5];
    const float* b_dt   = (const float*)d_in[6];
    const float* A_log  = (const float*)d_in[7];
    const float* D_skip = (const float*)d_in[8];
    const float* W_out  = (const float*)d_in[9];

    char* ws = (char*)d_ws;
    bf16_t* xz    = (bf16_t*)(ws + 0);            // [M,4096] bf16   33,554,432 B
    bf16_t* xcb   = (bf16_t*)(ws + 33554432);     // [M,2048] bf16   16,777,216 B
    float*  dlt   = (float*) (ws + 50331648);     // [M,2048] f32    33,554,432 B
    float*  ysv   = (float*) (ws + 83886080);     // [M,2048] f32    33,554,432 B
    float*  xdbl  = (float*) (ws + 117440512);    // [M,96]  f32      1,572,864 B
    bf16_t* dtb   = (bf16_t*)(ws + 119013376);    // [M,64]  bf16       524,288 B
    bf16_t* Wxb   = (bf16_t*)(ws + 119537664);    // [96,2048]          393,216 B
    bf16_t* Wdb   = (bf16_t*)(ws + 119930880);    // [2048,64]          262,144 B
    bf16_t* Wob   = (bf16_t*)(ws + 120193024);    // [1024,2048]      4,194,304 B
    bf16_t* hsb   = (bf16_t*)(ws + 124387328);    // [M,1024]         8,388,608 B (dead after in_proj)
    bf16_t* Wib   = (bf16_t*)(ws + 132775936);    // [4096,1024]      8,388,608 B (dead after in_proj)
    float*  hloc  = (float*) (ws + 124387328);    // [2,NC,2048,16]   8,388,608 B (aliases hsb)
    float*  aprod = (float*) (ws + 132775936);    // [2,NC,2048,16]   8,388,608 B (aliases Wib)
    float*  Hin   = (float*) (ws + 141164544);    // [2,NC,2048,16]   8,388,608 B
    bf16_t* yg    = (bf16_t*)(ws + 50331648);     // aliases dlt (dead after scan)
    // total ws used: 149,553,152 B

    // 0. casts
    castf2b_kernel<<<(MTOK*DMODEL)/256, 256, 0, stream>>>(hs,    hsb, MTOK*DMODEL);
    castf2b_kernel<<<(4096*1024)/256,  256, 0, stream>>>(W_in,  Wib, 4096*1024);
    castf2b_kernel<<<(96*2048)/256,    256, 0, stream>>>(W_xp,  Wxb, 96*2048);
    castf2b_kernel<<<(2048*64)/256,    256, 0, stream>>>(W_dt,  Wdb, 2048*64);
    castf2b_kernel<<<(1024*2048)/256,  256, 0, stream>>>(W_out, Wob, 1024*2048);

    // 1. in_proj
    gemm_nt<4,4,1,1><<<dim3(MTOK/128, 4096/128, 1), 256, 0, stream>>>(
        hsb, Wib, DMODEL, DMODEL, DMODEL, 2*DINNER, nullptr, xz, nullptr);

    // 2. conv + SiLU
    conv_silu_kernel<<<MTOK*DINNER/256, 256, 0, stream>>>(xz, conv_w, conv_b, xcb);

    // 3. x_proj (split-K=8, atomic fp32)
    hipMemsetAsync(xdbl, 0, (size_t)MTOK*96*4, stream);
    gemm_nt<4,3,2,8><<<dim3(MTOK/128, 1, 8), 256, 0, stream>>>(
        xcb, Wxb, DINNER, DINNER, DINNER, 96, xdbl, nullptr, nullptr);

    // 4. dt cast
    dtcast_kernel<<<MTOK*64/256, 256, 0, stream>>>(xdbl, dtb);

    // 5. delta = softplus(dt @ W_dt^T + b_dt)
    gemm_nt<4,4,3,1><<<dim3(MTOK/128, DINNER/128, 1), 256, 0, stream>>>(
        dtb, Wdb, DTRANK, DTRANK, DTRANK, DINNER, dlt, nullptr, b_dt);

    // 6. chunked selective scan
    scan_part1<<<NBATCH*NC*8, 256, 0, stream>>>(dlt, xcb, xdbl, A_log, hloc, aprod);
    scan_part2<<<(NBATCH*DINNER*16)/256, 256, 0, stream>>>(hloc, aprod, Hin);
    scan_part3<<<NBATCH*NC*8, 256, 0, stream>>>(dlt, xcb, xdbl, A_log, Hin, ysv);

    // 7. skip + gate
    gate_kernel<<<MTOK*DINNER/256, 256, 0, stream>>>(xz, xcb, ysv, D_skip, yg);

    // 8. out_proj -> fp32 d_out
    gemm_nt<4,4,4,1><<<dim3(MTOK/128, DMODEL/128, 1), 256, 0, stream>>>(
        yg, Wob, DINNER, DINNER, DINNER, DMODEL, (float*)d_out, nullptr, nullptr);
}

// Round 4
// 377.960 us; speedup vs baseline: 2.6471x; 1.1270x over previous
//
#include <hip/hip_runtime.h>
#include <hip/hip_bf16.h>
#include <math.h>

#define L_SEQ  2048
#define NBATCH 2
#define DMODEL 1024
#define DINNER 2048
#define DSTATE 16
#define DTRANK 64
#define MTOK   (NBATCH * L_SEQ)   // 4096
#define NC     32                 // scan chunks per sequence
#define TCH    (L_SEQ / NC)       // 64 steps per chunk

typedef __hip_bfloat16 bf16_t;
typedef __attribute__((ext_vector_type(8))) short bf16x8;   // 8 bf16 = 4 VGPRs
typedef __attribute__((ext_vector_type(4))) float f32x4;

__device__ __forceinline__ float  bf2f(bf16_t v) { return __bfloat162float(v); }
__device__ __forceinline__ bf16_t f2bf(float v)  { return __float2bfloat16(v); }
__device__ __forceinline__ unsigned short f2bfu(float v) {
    bf16_t b = __float2bfloat16(v);
    return *(unsigned short*)&b;
}

// fp32 -> bf16 cast, 4 elements/thread
__global__ __launch_bounds__(256)
void castf2b_kernel(const float4* __restrict__ in, ushort4* __restrict__ out, int n4)
{
    int i = blockIdx.x * 256 + threadIdx.x;
    if (i < n4) {
        float4 v = in[i];
        ushort4 o;
        o.x = f2bfu(v.x); o.y = f2bfu(v.y); o.z = f2bfu(v.z); o.w = f2bfu(v.w);
        out[i] = o;
    }
}

// NT GEMM: C[m,n] = sum_k A[m,k] * Bw[n,k], K-contiguous rows, bf16 in, constexpr dims.
// LDS layout: row-major [row][32 k] with k-quarter XOR swizzle: global quarter q of row r
// lives at slot (q + (r>>1)) & 3  -> fragment ds_read_b128 is 2-way bank (free, m136).
// EPI: 1 = bf16 store; 2 = fp32 atomicAdd (split-K); 3 = softplus(acc+bias) fp32; 4 = fp32 store
template<int TM, int TN, int EPI, int KSPLIT, int K, int LDA, int LDB, int LDO>
__global__ __launch_bounds__(256)
void gemm_nt(const bf16_t* __restrict__ A, const bf16_t* __restrict__ Bw,
             float* __restrict__ outF, bf16_t* __restrict__ outB,
             const float* __restrict__ bias)
{
    constexpr int BM = 32 * TM, BN = 32 * TN;
    constexpr int NA   = BM / 16;          // A staging issues (64 lanes x 16 B each)
    constexpr int NISS = NA + BN / 16;
    __shared__ bf16_t As[BM * 32];
    __shared__ bf16_t Bs[BN * 32];

    const int tid  = threadIdx.x;
    const int w    = tid >> 6;
    const int lane = tid & 63;
    const int wm   = w >> 1, wn = w & 1;
    const int bm   = blockIdx.x * BM;
    const int bn   = blockIdx.y * BN;
    constexpr int Kc = K / KSPLIT;
    const int kbeg = blockIdx.z * Kc;

    f32x4 acc[TM][TN];
#pragma unroll
    for (int i = 0; i < TM; ++i)
#pragma unroll
        for (int j = 0; j < TN; ++j)
            acc[i][j] = (f32x4){0.f, 0.f, 0.f, 0.f};

    const int mr = lane & 15;
    const int kq = lane >> 4;

    for (int kt = kbeg; kt < kbeg + Kc; kt += 32) {
        // ---- stage A,B tiles (async DMA, 16 B/lane; source address carries the swizzle)
#pragma unroll
        for (int ii = 0; ii < (NISS + 3) / 4; ++ii) {
            int it = ii * 4 + w;
            if (it < NISS) {
                int isA   = (it < NA);
                int itb   = isA ? it : it - NA;
                int chunk = itb * 64 + lane;
                int row   = chunk >> 2;
                int qs    = chunk & 3;
                int q     = (qs - (row >> 1)) & 3;          // global quarter at this slot
                const bf16_t* gp = isA
                    ? A  + (size_t)(bm + row) * LDA + kt + q * 8
                    : Bw + (size_t)(bn + row) * LDB + kt + q * 8;
                char* lp = isA ? (char*)As + it * 1024 : (char*)Bs + itb * 1024;
                __builtin_amdgcn_global_load_lds(
                    (const __attribute__((address_space(1))) void*)gp,
                    (__attribute__((address_space(3))) void*)lp, 16, 0, 0);
            }
        }
        __syncthreads();

        // ---- fragments (swizzled slot) + MFMA
        bf16x8 af[TM], bfv[TN];
#pragma unroll
        for (int mi = 0; mi < TM; ++mi) {
            int rA = wm * 16 * TM + mi * 16 + mr;
            af[mi] = *(const bf16x8*)&As[rA * 32 + (((kq + (rA >> 1)) & 3) * 8)];
        }
#pragma unroll
        for (int ni = 0; ni < TN; ++ni) {
            int rB = wn * 16 * TN + ni * 16 + mr;
            bfv[ni] = *(const bf16x8*)&Bs[rB * 32 + (((kq + (rB >> 1)) & 3) * 8)];
        }
#pragma unroll
        for (int mi = 0; mi < TM; ++mi)
#pragma unroll
            for (int ni = 0; ni < TN; ++ni)
                acc[mi][ni] = __builtin_amdgcn_mfma_f32_16x16x32_bf16(
                    af[mi], bfv[ni], acc[mi][ni], 0, 0, 0);
        __syncthreads();
    }

    // ---- epilogue: C/D layout col=lane&15, row=(lane>>4)*4+reg  [m89/m91]
#pragma unroll
    for (int mi = 0; mi < TM; ++mi) {
#pragma unroll
        for (int ni = 0; ni < TN; ++ni) {
#pragma unroll
            for (int r = 0; r < 4; ++r) {
                int row = bm + wm * 16 * TM + mi * 16 + kq * 4 + r;
                int col = bn + wn * 16 * TN + ni * 16 + mr;
                float v = acc[mi][ni][r];
                if (EPI == 1) {
                    outB[(size_t)row * LDO + col] = f2bf(v);
                } else if (EPI == 2) {
                    atomicAdd(&outF[(size_t)row * LDO + col], v);
                } else if (EPI == 3) {
                    v += bias[col];
                    v = (v > 20.f) ? v : log1pf(__expf(v));
                    outF[(size_t)row * LDO + col] = v;
                } else {
                    outF[(size_t)row * LDO + col] = v;
                }
            }
        }
    }
}

// depthwise causal conv (width 4) + bias + SiLU. x = first half of xz [M, 4096] bf16.
__global__ __launch_bounds__(256)
void conv_silu_kernel(const bf16_t* __restrict__ xz, const float* __restrict__ cw,
                      const float* __restrict__ cb, bf16_t* __restrict__ xcb)
{
    int idx = blockIdx.x * 256 + threadIdx.x;
    int d = idx & (DINNER - 1);
    int m = idx >> 11;
    int t = m & (L_SEQ - 1);
    float acc = cb[d];
#pragma unroll
    for (int k = 0; k < 4; ++k) {
        int tt = t - 3 + k;
        if (tt >= 0)
            acc += bf2f(xz[(size_t)(m - 3 + k) * (2 * DINNER) + d]) * cw[d * 4 + k];
    }
    float s = acc / (1.f + __expf(-acc));
    xcb[idx] = f2bf(s);
}

// cast dt columns (0..63) of xdbl [M,96] fp32 -> dtb [M,64] bf16
__global__ __launch_bounds__(256)
void dtcast_kernel(const float* __restrict__ xdbl, bf16_t* __restrict__ dtb)
{
    int i = blockIdx.x * 256 + threadIdx.x;
    int m = i >> 6, r = i & 63;
    dtb[i] = f2bf(xdbl[(size_t)m * 96 + r]);
}

// ---------- chunked selective scan ----------
// Pass 1: per (b, chunk, d): chunk-local scan from h=0 -> final h; decay prod = exp(A*sum(dt)).
__global__ __launch_bounds__(256)
void scan_part1(const float* __restrict__ dlt, const bf16_t* __restrict__ u,
                const float* __restrict__ xdbl, const float* __restrict__ A_log,
                float* __restrict__ hloc, float* __restrict__ aprod)
{
    int bx = blockIdx.x;
    int dblk = bx & 7;
    int c    = (bx >> 3) & (NC - 1);
    int b    = bx >> 8;
    int d    = dblk * 256 + threadIdx.x;
    int m0   = b * L_SEQ + c * TCH;

    __shared__ float BC[TCH][32];   // [:,0:16]=B, [:,16:32]=C
    for (int i = threadIdx.x; i < TCH * 32; i += 256) {
        int r = i >> 5, cc = i & 31;
        BC[r][cc] = xdbl[(size_t)(m0 + r) * 96 + 64 + cc];
    }
    __syncthreads();

    float Av[16];
#pragma unroll
    for (int n = 0; n < 16; ++n) Av[n] = -__expf(A_log[d * 16 + n]);

    const float*  dp = dlt + (size_t)m0 * DINNER + d;
    const bf16_t* up = u   + (size_t)m0 * DINNER + d;

    float h[16];
#pragma unroll
    for (int n = 0; n < 16; ++n) h[n] = 0.f;
    float sumdt = 0.f;

    float dv[8], uv[8];
#pragma unroll
    for (int j = 0; j < 8; ++j) {
        dv[j] = dp[(size_t)j * DINNER];
        uv[j] = bf2f(up[(size_t)j * DINNER]);
    }
    for (int tb = 0; tb < TCH; tb += 8) {
        float dn[8] = {0}, un[8] = {0};
        if (tb + 8 < TCH) {
#pragma unroll
            for (int j = 0; j < 8; ++j) {
                dn[j] = dp[(size_t)(tb + 8 + j) * DINNER];
                un[j] = bf2f(up[(size_t)(tb + 8 + j) * DINNER]);
            }
        }
#pragma unroll
        for (int j = 0; j < 8; ++j) {
            int t = tb + j;
            float dt_t = dv[j];
            float dbu  = dt_t * uv[j];
            sumdt += dt_t;
#pragma unroll
            for (int n = 0; n < 16; ++n) {
                float dA = __expf(dt_t * Av[n]);
                h[n] = fmaf(dA, h[n], dbu * BC[t][n]);
            }
        }
#pragma unroll
        for (int j = 0; j < 8; ++j) { dv[j] = dn[j]; uv[j] = un[j]; }
    }

    size_t o = (((size_t)b * NC + c) * DINNER + d) * 16;
#pragma unroll
    for (int n = 0; n < 16; n += 4) {
        *(f32x4*)&hloc[o + n] = (f32x4){h[n], h[n+1], h[n+2], h[n+3]};
        *(f32x4*)&aprod[o + n] = (f32x4){__expf(sumdt * Av[n]),   __expf(sumdt * Av[n+1]),
                                         __expf(sumdt * Av[n+2]), __expf(sumdt * Av[n+3])};
    }
}

// Pass 2: serial carry over chunks: Hin[c] = state entering chunk c.
__global__ __launch_bounds__(256)
void scan_part2(const float* __restrict__ hloc, const float* __restrict__ aprod,
                float* __restrict__ Hin)
{
    int idx = blockIdx.x * 256 + threadIdx.x;   // < 2*DINNER*16
    int b  = idx >> 15;
    int dn = idx & 32767;
    float H = 0.f;
    size_t o = (size_t)b * NC * DINNER * 16 + dn;
    constexpr size_t CS = (size_t)DINNER * 16;
    float a = aprod[o], hl = hloc[o];
    for (int c = 0; c < NC; ++c) {
        float an = 0.f, hn = 0.f;
        if (c + 1 < NC) { an = aprod[o + (c + 1) * CS]; hn = hloc[o + (c + 1) * CS]; }
        Hin[o + c * CS] = H;
        H = fmaf(a, H, hl);
        a = an; hl = hn;
    }
}

// Pass 3: chunk scan seeded with Hin; fused skip + output gate -> yg bf16.
__global__ __launch_bounds__(256)
void scan_part3(const float* __restrict__ dlt, const bf16_t* __restrict__ u,
                const float* __restrict__ xdbl, const float* __restrict__ A_log,
                const float* __restrict__ Hin, const bf16_t* __restrict__ xz,
                const float* __restrict__ Dskip, bf16_t* __restrict__ yg)
{
    int bx = blockIdx.x;
    int dblk = bx & 7;
    int c    = (bx >> 3) & (NC - 1);
    int b    = bx >> 8;
    int d    = dblk * 256 + threadIdx.x;
    int m0   = b * L_SEQ + c * TCH;

    __shared__ float BC[TCH][32];
    for (int i = threadIdx.x; i < TCH * 32; i += 256) {
        int r = i >> 5, cc = i & 31;
        BC[r][cc] = xdbl[(size_t)(m0 + r) * 96 + 64 + cc];
    }
    __syncthreads();

    float Av[16];
#pragma unroll
    for (int n = 0; n < 16; ++n) Av[n] = -__expf(A_log[d * 16 + n]);
    const float Dsk = Dskip[d];

    const float*  dp = dlt + (size_t)m0 * DINNER + d;
    const bf16_t* up = u   + (size_t)m0 * DINNER + d;
    const bf16_t* zp = xz  + (size_t)m0 * (2 * DINNER) + DINNER + d;
    bf16_t* yo = yg + (size_t)m0 * DINNER + d;

    size_t o = (((size_t)b * NC + c) * DINNER + d) * 16;
    float h[16];
#pragma unroll
    for (int n = 0; n < 16; n += 4) {
        f32x4 hv = *(const f32x4*)&Hin[o + n];
        h[n] = hv[0]; h[n+1] = hv[1]; h[n+2] = hv[2]; h[n+3] = hv[3];
    }

    float dv[8], uv[8], zv[8];
#pragma unroll
    for (int j = 0; j < 8; ++j) {
        dv[j] = dp[(size_t)j * DINNER];
        uv[j] = bf2f(up[(size_t)j * DINNER]);
        zv[j] = bf2f(zp[(size_t)j * (2 * DINNER)]);
    }
    for (int tb = 0; tb < TCH; tb += 8) {
        float dn[8] = {0}, un[8] = {0}, zn[8] = {0};
        if (tb + 8 < TCH) {
#pragma unroll
            for (int j = 0; j < 8; ++j) {
                dn[j] = dp[(size_t)(tb + 8 + j) * DINNER];
                un[j] = bf2f(up[(size_t)(tb + 8 + j) * DINNER]);
                zn[j] = bf2f(zp[(size_t)(tb + 8 + j) * (2 * DINNER)]);
            }
        }
#pragma unroll
        for (int j = 0; j < 8; ++j) {
            int t = tb + j;
            float dt_t = dv[j];
            float dbu  = dt_t * uv[j];
            float y0 = 0.f, y1 = 0.f, y2 = 0.f, y3 = 0.f;
#pragma unroll
            for (int n = 0; n < 16; n += 4) {
                float dA0 = __expf(dt_t * Av[n]);
                float dA1 = __expf(dt_t * Av[n+1]);
                float dA2 = __expf(dt_t * Av[n+2]);
                float dA3 = __expf(dt_t * Av[n+3]);
                h[n]   = fmaf(dA0, h[n],   dbu * BC[t][n]);
                h[n+1] = fmaf(dA1, h[n+1], dbu * BC[t][n+1]);
                h[n+2] = fmaf(dA2, h[n+2], dbu * BC[t][n+2]);
                h[n+3] = fmaf(dA3, h[n+3], dbu * BC[t][n+3]);
                y0 = fmaf(h[n],   BC[t][16+n],   y0);
                y1 = fmaf(h[n+1], BC[t][16+n+1], y1);
                y2 = fmaf(h[n+2], BC[t][16+n+2], y2);
                y3 = fmaf(h[n+3], BC[t][16+n+3], y3);
            }
            float yv = (y0 + y1) + (y2 + y3) + uv[j] * Dsk;   // u IS silu(conv(x))
            float z  = zv[j];
            yo[(size_t)t * DINNER] = f2bf(yv * (z / (1.f + __expf(-z))));
        }
#pragma unroll
        for (int j = 0; j < 8; ++j) { dv[j] = dn[j]; uv[j] = un[j]; zv[j] = zn[j]; }
    }
}

extern "C" void kernel_launch(void* const* d_in, const int* in_sizes, int n_in,
                              void* d_out, int out_size, void* d_ws, size_t ws_size,
                              hipStream_t stream)
{
    (void)in_sizes; (void)n_in; (void)out_size; (void)ws_size;
    const float* hs     = (const float*)d_in[0];
    const float* W_in   = (const float*)d_in[1];
    const float* conv_w = (const float*)d_in[2];
    const float* conv_b = (const float*)d_in[3];
    const float* W_xp   = (const float*)d_in[4];
    const float* W_dt   = (const float*)d_in[5];
    const float* b_dt   = (const float*)d_in[6];
    const float* A_log  = (const float*)d_in[7];
    const float* D_skip = (const float*)d_in[8];
    const float* W_out  = (const float*)d_in[9];

    char* ws = (char*)d_ws;
    bf16_t* xz    = (bf16_t*)(ws + 0);            // [M,4096] bf16   33,554,432
    bf16_t* xcb   = (bf16_t*)(ws + 33554432);     // [M,2048] bf16   16,777,216
    float*  dlt   = (float*) (ws + 50331648);     // [M,2048] f32    33,554,432
    bf16_t* yg    = (bf16_t*)(ws + 83886080);     // [M,2048] bf16   16,777,216
    float*  xdbl  = (float*) (ws + 100663296);    // [M,96]  f32      1,572,864
    bf16_t* dtb   = (bf16_t*)(ws + 102236160);    // [M,64]  bf16       524,288
    bf16_t* Wxb   = (bf16_t*)(ws + 102760448);    // [96,2048]          393,216
    bf16_t* Wdb   = (bf16_t*)(ws + 103153664);    // [2048,64]          262,144
    bf16_t* Wob   = (bf16_t*)(ws + 103415808);    // [1024,2048]      4,194,304
    bf16_t* hsb   = (bf16_t*)(ws + 107610112);    // [M,1024]         8,388,608 (dead after in_proj)
    bf16_t* Wib   = (bf16_t*)(ws + 115998720);    // [4096,1024]      8,388,608 (dead after in_proj)
    float*  hloc  = (float*) (ws + 107610112);    // [2,NC,2048,16]   (aliases hsb)
    float*  aprod = (float*) (ws + 115998720);    // [2,NC,2048,16]   (aliases Wib)
    float*  Hin   = (float*) (ws + 124387328);    // [2,NC,2048,16]   8,388,608
    // total: 132,775,936 B

    // 0. casts (float4 -> 4x bf16)
    castf2b_kernel<<<(MTOK*DMODEL/4+255)/256, 256, 0, stream>>>((const float4*)hs,    (ushort4*)hsb, MTOK*DMODEL/4);
    castf2b_kernel<<<(4096*1024/4+255)/256,  256, 0, stream>>>((const float4*)W_in,  (ushort4*)Wib, 4096*1024/4);
    castf2b_kernel<<<(96*2048/4+255)/256,    256, 0, stream>>>((const float4*)W_xp,  (ushort4*)Wxb, 96*2048/4);
    castf2b_kernel<<<(2048*64/4+255)/256,    256, 0, stream>>>((const float4*)W_dt,  (ushort4*)Wdb, 2048*64/4);
    castf2b_kernel<<<(1024*2048/4+255)/256,  256, 0, stream>>>((const float4*)W_out, (ushort4*)Wob, 1024*2048/4);

    // 1. in_proj: xz = hs @ W_in^T   (M=4096, N=4096, K=1024)
    gemm_nt<4,4,1,1, 1024,1024,1024,4096><<<dim3(MTOK/128, 4096/128, 1), 256, 0, stream>>>(
        hsb, Wib, nullptr, xz, nullptr);

    // 2. conv + SiLU
    conv_silu_kernel<<<MTOK*DINNER/256, 256, 0, stream>>>(xz, conv_w, conv_b, xcb);

    // 3. x_proj (N=96, K=2048) split-K=8 atomic fp32
    hipMemsetAsync(xdbl, 0, (size_t)MTOK*96*4, stream);
    gemm_nt<4,3,2,8, 2048,2048,2048,96><<<dim3(MTOK/128, 1, 8), 256, 0, stream>>>(
        xcb, Wxb, xdbl, nullptr, nullptr);

    // 4. dt cast
    dtcast_kernel<<<MTOK*64/256, 256, 0, stream>>>(xdbl, dtb);

    // 5. delta = softplus(dt @ W_dt^T + b_dt)  (N=2048, K=64)
    gemm_nt<4,4,3,1, 64,64,64,2048><<<dim3(MTOK/128, DINNER/128, 1), 256, 0, stream>>>(
        dtb, Wdb, dlt, nullptr, b_dt);

    // 6. chunked selective scan (part3 fuses skip + gate)
    scan_part1<<<NBATCH*NC*8, 256, 0, stream>>>(dlt, xcb, xdbl, A_log, hloc, aprod);
    scan_part2<<<(NBATCH*DINNER*16)/256, 256, 0, stream>>>(hloc, aprod, Hin);
    scan_part3<<<NBATCH*NC*8, 256, 0, stream>>>(dlt, xcb, xdbl, A_log, Hin, xz, D_skip, yg);

    // 7. out_proj: out = y @ W_out^T  (N=1024, K=2048) -> fp32 d_out
    gemm_nt<4,4,4,1, 2048,2048,2048,1024><<<dim3(MTOK/128, DMODEL/128, 1), 256, 0, stream>>>(
        yg, Wob, (float*)d_out, nullptr, nullptr);
}